// Round 1
// baseline (261.276 us; speedup 1.0000x reference)
//
#include <hip/hip_runtime.h>
#include <math.h>

#define PI_F 3.14159265358979323846f
#define TWO_PI_F 6.28318530717958647692f

// ---------------- sector map (matches reference _polar_masks) ----------------
// hm, wm are indices in the *shifted* (mask) coordinate frame.
__device__ __forceinline__ int sector_id(int hm, int wm) {
    const float step = 2.0f / 511.0f;               // linspace(-1,1,512) step
    float y = -1.0f + step * (float)hm;
    float x = -1.0f + step * (float)wm;
    float radius = sqrtf(x * x + y * y);
    float r = radius / sqrtf(2.0f);                 // radius.max() == sqrt(2) exactly
    float a = atan2f(y, x);
    a = fmodf(a, PI_F);
    if (a < 0.0f) a += PI_F;                        // jnp.remainder(angle, pi) -> [0, pi)

    const float rstep = (0.9f - 0.08f) / 3.0f;
    const float re0 = 0.08f;
    const float re1 = 0.08f + rstep;
    const float re2 = 0.08f + 2.0f * rstep;
    const float re3 = 0.9f;
    int rb;
    if      (r >= re0 && r < re1)  rb = 0;
    else if (r >= re1 && r < re2)  rb = 1;
    else if (r >= re2 && r <= re3) rb = 2;          // last radial bin inclusive
    else return -1;

    const float astep = PI_F / 8.0f;
    int ab = 7;                                     // last angular bin catches a >= t7
    #pragma unroll
    for (int i = 0; i < 7; ++i) {
        float t0 = astep * (float)i;
        float t1 = astep * (float)(i + 1);
        if (a >= t0 && a < t1) { ab = i; break; }
    }
    return rb * 8 + ab;
}

__device__ __forceinline__ float hannf(int i) {
    // 0.5*(1 - cos(2*pi*i/511)), periodic=False window of length 512
    return 0.5f * (1.0f - __cosf(TWO_PI_F * (float)i / 511.0f));
}

// ---------------- 512-pt Stockham radix-2 FFT in LDS (forward) ----------------
// 256 threads, ping-pong between bufA/bufB. Result pointer returned via *result,
// in natural order. Verified index algebra: stage s=2^k, m=ncur/2, s*m==256.
__device__ __forceinline__ void fft512(float2* bufA, float2* bufB, int t, float2** result) {
    float2* src = bufA;
    float2* dst = bufB;
    int ncur = 512;
    #pragma unroll
    for (int stage = 0; stage < 9; ++stage) {
        int s = 1 << stage;
        int q = t & (s - 1);
        int p = t >> stage;
        float2 a = src[q + s * p];
        float2 b = src[q + s * p + 256];            // s*m == 256 at every stage
        float ang = -TWO_PI_F * (float)p / (float)ncur;
        float sn, cs;
        __sincosf(ang, &sn, &cs);
        float2 apb = make_float2(a.x + b.x, a.y + b.y);
        float dx = a.x - b.x, dy = a.y - b.y;
        float2 tw = make_float2(dx * cs - dy * sn, dx * sn + dy * cs);
        dst[q + 2 * s * p] = apb;
        dst[q + 2 * s * p + s] = tw;
        __syncthreads();
        float2* tmp = src; src = dst; dst = tmp;
        ncur >>= 1;
    }
    *result = src;
}

// ---------------- kernel 1: zero the accumulators ----------------
__global__ void zero_kernel(float* p, int n) {
    int i = blockIdx.x * 256 + threadIdx.x;
    if (i < n) p[i] = 0.0f;
}

// ---------------- kernel 2: sector pixel counts (mask_sum) ----------------
__global__ __launch_bounds__(256) void counts_kernel(float* __restrict__ counts) {
    __shared__ float bins[24];
    int t = threadIdx.x;
    if (t < 24) bins[t] = 0.0f;
    __syncthreads();
    int idx = blockIdx.x * 256 + t;                 // 0 .. 262143
    int hm = idx >> 9, wm = idx & 511;
    int s = sector_id(hm, wm);
    if (s >= 0) atomicAdd(&bins[s], 1.0f);
    __syncthreads();
    if (t < 24) atomicAdd(&counts[t], bins[t]);
}

// ---------------- kernel 3: luma + window + row FFT ----------------
// One block per (img, row). Writes transposed: buf[img][w][h], w in [0,256]
// (Hermitian symmetry of real-input row FFT: only w<=256 needed).
__global__ __launch_bounds__(256) void rowfft_kernel(const float* __restrict__ pred,
                                                     const float* __restrict__ tgt,
                                                     float2* __restrict__ buf) {
    __shared__ float2 lds[2][512];
    int blk = blockIdx.x;
    int img = blk >> 9;
    int h = blk & 511;
    int t = threadIdx.x;
    const float* base = (img < 16) ? (pred + (size_t)img * 3 * 262144)
                                   : (tgt  + (size_t)(img - 16) * 3 * 262144);
    float wh = hannf(h);
    #pragma unroll
    for (int k = 0; k < 2; ++k) {
        int w = t + k * 256;
        size_t off = (size_t)h * 512 + w;
        float r = base[off];
        float g = base[262144 + off];
        float b = base[524288 + off];
        float luma = 0.2989f * r + 0.587f * g + 0.114f * b;
        lds[0][w] = make_float2(luma * (wh * hannf(w)), 0.0f);
    }
    __syncthreads();
    float2* res;
    fft512(lds[0], lds[1], t, &res);
    size_t obase = (size_t)(img * 257) * 512;
    buf[obase + (size_t)t * 512 + h] = res[t];
    if (t == 0) buf[obase + (size_t)256 * 512 + h] = res[256];
}

// ---------------- kernel 4: column FFT + log-mag + sector reduction ----------------
// One block per (img, w), w in [0,256]. Hermitian mirror covers w in [257,511].
__global__ __launch_bounds__(256) void colfft_kernel(const float2* __restrict__ buf,
                                                     float* __restrict__ acc) {
    __shared__ float2 lds[2][512];
    __shared__ float bins[24];
    int blk = blockIdx.x;
    int img = blk / 257;
    int w = blk % 257;
    int t = threadIdx.x;
    if (t < 24) bins[t] = 0.0f;
    const float2* col = buf + (size_t)(img * 257 + w) * 512;
    lds[0][t] = col[t];
    lds[0][t + 256] = col[t + 256];
    __syncthreads();
    float2* res;
    fft512(lds[0], lds[1], t, &res);
    bool mir = (w >= 1 && w <= 255);
    #pragma unroll
    for (int k = 0; k < 2; ++k) {
        int h = t + k * 256;
        float2 v = res[h];
        float mag = log1pf(sqrtf(v.x * v.x + v.y * v.y));
        int hm = (h + 256) & 511;                   // fftshift via index remap
        int wm = (w + 256) & 511;
        int s = sector_id(hm, wm);
        if (s >= 0) atomicAdd(&bins[s], mag);
        if (mir) {
            int h2 = (512 - h) & 511;               // |F[-h, -w]| == |F[h, w]|
            int w2 = 512 - w;
            int hm2 = (h2 + 256) & 511;
            int wm2 = (w2 + 256) & 511;
            int s2 = sector_id(hm2, wm2);
            if (s2 >= 0) atomicAdd(&bins[s2], mag);
        }
    }
    __syncthreads();
    if (t < 24) atomicAdd(&acc[img * 24 + t], bins[t]);
}

// ---------------- kernel 5: energies -> charbonnier -> weighted mean ----------------
__global__ __launch_bounds__(384) void final_kernel(const float* __restrict__ acc,
                                                    const float* __restrict__ counts,
                                                    const float* __restrict__ rw,
                                                    float* __restrict__ out) {
    __shared__ float ep[384], et[384], red[384];
    int t = threadIdx.x;                            // t = b*24 + r*8 + a
    int b = t / 24;
    int s = t % 24;
    int r = s >> 3;
    float cnt = fmaxf(counts[s], 1e-6f);
    ep[t] = acc[b * 24 + s] / cnt;
    et[t] = acc[(16 + b) * 24 + s] / cnt;
    __syncthreads();
    int gbase = b * 24 + r * 8;
    float sp = 0.0f, st = 0.0f;
    #pragma unroll
    for (int a = 0; a < 8; ++a) { sp += ep[gbase + a]; st += et[gbase + a]; }
    float pe = ep[t] / fmaxf(sp, 1e-6f);
    float te = et[t] / fmaxf(st, 1e-6f);
    float d = pe - te;
    float dist = sqrtf(d * d + 1e-6f);
    red[t] = dist * rw[r];
    __syncthreads();
    if (t == 0) {
        float tot = 0.0f;
        for (int i = 0; i < 384; ++i) tot += red[i];
        out[0] = tot / 384.0f;
    }
}

extern "C" void kernel_launch(void* const* d_in, const int* in_sizes, int n_in,
                              void* d_out, int out_size, void* d_ws, size_t ws_size,
                              hipStream_t stream) {
    const float* pred = (const float*)d_in[0];
    const float* tgt  = (const float*)d_in[1];
    const float* rw   = (const float*)d_in[2];

    char* ws = (char*)d_ws;
    float* acc    = (float*)ws;                     // 32*24 floats
    float* counts = acc + 32 * 24;                  // 24 floats
    float2* buf   = (float2*)(ws + 4096);           // 32*257*512 complex = 33.7 MB

    zero_kernel<<<4, 256, 0, stream>>>(acc, 32 * 24 + 24);
    counts_kernel<<<1024, 256, 0, stream>>>(counts);
    rowfft_kernel<<<32 * 512, 256, 0, stream>>>(pred, tgt, buf);
    colfft_kernel<<<32 * 257, 256, 0, stream>>>(buf, acc);
    final_kernel<<<1, 384, 0, stream>>>(acc, counts, rw, (float*)d_out);
}

// Round 2
// 243.151 us; speedup vs baseline: 1.0745x; 1.0745x over previous
//
#include <hip/hip_runtime.h>
#include <math.h>

#define PI_F 3.14159265358979323846f
#define TWO_PI_F 6.28318530717958647692f

// ---------------- sector map (matches reference _polar_masks) ----------------
// hm, wm are indices in the *shifted* (mask) coordinate frame.
__device__ __forceinline__ int sector_id(int hm, int wm) {
    const float step = 2.0f / 511.0f;               // linspace(-1,1,512) step
    float y = -1.0f + step * (float)hm;
    float x = -1.0f + step * (float)wm;
    float radius = sqrtf(x * x + y * y);
    float r = radius / sqrtf(2.0f);                 // radius.max() == sqrt(2) exactly
    float a = atan2f(y, x);
    a = fmodf(a, PI_F);
    if (a < 0.0f) a += PI_F;                        // jnp.remainder(angle, pi) -> [0, pi)

    const float rstep = (0.9f - 0.08f) / 3.0f;
    const float re0 = 0.08f;
    const float re1 = 0.08f + rstep;
    const float re2 = 0.08f + 2.0f * rstep;
    const float re3 = 0.9f;
    int rb;
    if      (r >= re0 && r < re1)  rb = 0;
    else if (r >= re1 && r < re2)  rb = 1;
    else if (r >= re2 && r <= re3) rb = 2;          // last radial bin inclusive
    else return -1;

    const float astep = PI_F / 8.0f;
    int ab = 7;                                     // last angular bin catches a >= t7
    #pragma unroll
    for (int i = 0; i < 7; ++i) {
        float t0 = astep * (float)i;
        float t1 = astep * (float)(i + 1);
        if (a >= t0 && a < t1) { ab = i; break; }
    }
    return rb * 8 + ab;
}

__device__ __forceinline__ float hannf(int i) {
    // 0.5*(1 - cos(2*pi*i/511)), periodic=False window of length 512
    return 0.5f * (1.0f - __cosf(TWO_PI_F * (float)i / 511.0f));
}

// ---------------- 512-pt Stockham radix-2 FFT in LDS (forward) ----------------
// 256 threads, ping-pong bufA/bufB. tw[k] = (cos,sin) of -2*pi*k/512.
// Twiddle for stage: angle = -2*pi*p/(512>>stage) = -2*pi*(p<<stage)/512.
__device__ __forceinline__ float2* fft512(float2* bufA, float2* bufB,
                                          const float2* tw, int t) {
    float2* src = bufA;
    float2* dst = bufB;
    #pragma unroll
    for (int stage = 0; stage < 9; ++stage) {
        int s = 1 << stage;
        int q = t & (s - 1);
        int p = t >> stage;
        float2 a = src[q + s * p];
        float2 b = src[q + s * p + 256];            // s*m == 256 at every stage
        float2 tv = tw[p << stage];
        float2 apb = make_float2(a.x + b.x, a.y + b.y);
        float dx = a.x - b.x, dy = a.y - b.y;
        float2 twv = make_float2(dx * tv.x - dy * tv.y, dx * tv.y + dy * tv.x);
        dst[q + 2 * s * p] = apb;
        dst[q + 2 * s * p + s] = twv;
        __syncthreads();
        float2* tmp = src; src = dst; dst = tmp;
    }
    return src;
}

// ---------------- kernel 1: zero the accumulators ----------------
__global__ void zero_kernel(float* p, int n) {
    int i = blockIdx.x * 256 + threadIdx.x;
    if (i < n) p[i] = 0.0f;
}

// ---------------- kernel 2: sector map (transposed) + pixel counts ----------------
// mapT[wm*512 + hm] = sector id (255 = outside). Fused mask_sum histogram.
__global__ __launch_bounds__(256) void map_kernel(unsigned char* __restrict__ mapT,
                                                  float* __restrict__ counts) {
    __shared__ float bins[24];
    int t = threadIdx.x;
    if (t < 24) bins[t] = 0.0f;
    __syncthreads();
    int idx = blockIdx.x * 256 + t;                 // 0 .. 262143 = wm*512 + hm
    int wm = idx >> 9, hm = idx & 511;
    int s = sector_id(hm, wm);
    mapT[idx] = (unsigned char)(s < 0 ? 255 : s);
    if (s >= 0) atomicAdd(&bins[s], 1.0f);
    __syncthreads();
    if (t < 24) atomicAdd(&counts[t], bins[t]);
}

// ---------------- kernel 3: luma + window + row FFT (2 real rows packed) ----------------
// One block per (img, row-pair). Rows h0=2j (real part) and h1=2j+1 (imag part)
// share one complex FFT; Hermitian unpack yields both row spectra.
// Writes transposed: buf[img][k][h], k in [0,256]. float4 = (A.re,A.im,B.re,B.im)
// lands at adjacent h0,h1 -> one 16B store.
__global__ __launch_bounds__(256) void rowfft_kernel(const float* __restrict__ pred,
                                                     const float* __restrict__ tgt,
                                                     float2* __restrict__ buf) {
    __shared__ float2 lds[2][512];
    __shared__ float2 tw[256];
    int blk = blockIdx.x;                           // 32*256
    int img = blk >> 8;
    int hp = blk & 255;
    int h0 = 2 * hp, h1 = h0 + 1;
    int t = threadIdx.x;
    {
        float sn, cs;
        __sincosf(-TWO_PI_F * (float)t / 512.0f, &sn, &cs);
        tw[t] = make_float2(cs, sn);
    }
    const float* base = (img < 16) ? (pred + (size_t)img * 3 * 262144)
                                   : (tgt  + (size_t)(img - 16) * 3 * 262144);
    float wh0 = hannf(h0), wh1 = hannf(h1);
    #pragma unroll
    for (int k = 0; k < 2; ++k) {
        int w = t + k * 256;
        float ww = hannf(w);
        size_t off0 = (size_t)h0 * 512 + w;
        size_t off1 = off0 + 512;
        float l0 = 0.2989f * base[off0] + 0.587f * base[262144 + off0] + 0.114f * base[524288 + off0];
        float l1 = 0.2989f * base[off1] + 0.587f * base[262144 + off1] + 0.114f * base[524288 + off1];
        lds[0][w] = make_float2(l0 * (wh0 * ww), l1 * (wh1 * ww));
    }
    __syncthreads();
    float2* res = fft512(lds[0], lds[1], tw, t);
    size_t obase = (size_t)img * 257 * 512;
    {
        int k = t;                                  // k in [0,255]
        float2 zk = res[k];
        float2 zm = res[(512 - k) & 511];
        // A[k] = (Z[k]+conj(Z[-k]))/2 ; B[k] = -i(Z[k]-conj(Z[-k]))/2
        float4 o = make_float4(0.5f * (zk.x + zm.x), 0.5f * (zk.y - zm.y),
                               0.5f * (zk.y + zm.y), 0.5f * (zm.x - zk.x));
        ((float4*)buf)[(obase + (size_t)k * 512 + h0) >> 1] = o;
    }
    if (t == 0) {                                   // k = 256: Z self-conjugate index
        float2 z = res[256];
        float4 o = make_float4(z.x, 0.0f, z.y, 0.0f);
        ((float4*)buf)[(obase + (size_t)256 * 512 + h0) >> 1] = o;
    }
}

// ---------------- kernel 4: column FFT + log-mag + sector reduction ----------------
// One block per (img, w), w in [0,256]. Hermitian mirror covers w in [257,511].
__global__ __launch_bounds__(256) void colfft_kernel(const float2* __restrict__ buf,
                                                     const unsigned char* __restrict__ mapT,
                                                     float* __restrict__ acc) {
    __shared__ float2 lds[2][512];
    __shared__ float2 tw[256];
    __shared__ float bins[24];
    int blk = blockIdx.x;
    int img = blk / 257;
    int w = blk % 257;
    int t = threadIdx.x;
    if (t < 24) bins[t] = 0.0f;
    {
        float sn, cs;
        __sincosf(-TWO_PI_F * (float)t / 512.0f, &sn, &cs);
        tw[t] = make_float2(cs, sn);
    }
    const float2* col = buf + (size_t)(img * 257 + w) * 512;
    lds[0][t] = col[t];
    lds[0][t + 256] = col[t + 256];
    __syncthreads();
    float2* res = fft512(lds[0], lds[1], tw, t);
    int wm = (w + 256) & 511;                       // fftshift via index remap
    bool mir = (w >= 1 && w <= 255);
    int wm2 = (256 - w) & 511;                      // shifted coord of column 512-w
    const unsigned char* mcol  = mapT + (size_t)wm * 512;
    const unsigned char* mcol2 = mapT + (size_t)wm2 * 512;
    #pragma unroll
    for (int k = 0; k < 2; ++k) {
        int h = t + k * 256;
        float2 v = res[h];
        float mag = log1pf(sqrtf(v.x * v.x + v.y * v.y));
        int hm = (h + 256) & 511;
        int s = mcol[hm];
        if (s < 24) atomicAdd(&bins[s], mag);
        if (mir) {
            int hm2 = (256 - h) & 511;              // shifted coord of row (512-h)&511
            int s2 = mcol2[hm2];
            if (s2 < 24) atomicAdd(&bins[s2], mag); // |F[-h,-w]| == |F[h,w]|
        }
    }
    __syncthreads();
    if (t < 24) atomicAdd(&acc[img * 24 + t], bins[t]);
}

// ---------------- kernel 5: energies -> charbonnier -> weighted mean ----------------
__global__ __launch_bounds__(384) void final_kernel(const float* __restrict__ acc,
                                                    const float* __restrict__ counts,
                                                    const float* __restrict__ rw,
                                                    float* __restrict__ out) {
    __shared__ float ep[384], et[384], red[384];
    int t = threadIdx.x;                            // t = b*24 + r*8 + a
    int b = t / 24;
    int s = t % 24;
    int r = s >> 3;
    float cnt = fmaxf(counts[s], 1e-6f);
    ep[t] = acc[b * 24 + s] / cnt;
    et[t] = acc[(16 + b) * 24 + s] / cnt;
    __syncthreads();
    int gbase = b * 24 + r * 8;
    float sp = 0.0f, st = 0.0f;
    #pragma unroll
    for (int a = 0; a < 8; ++a) { sp += ep[gbase + a]; st += et[gbase + a]; }
    float pe = ep[t] / fmaxf(sp, 1e-6f);
    float te = et[t] / fmaxf(st, 1e-6f);
    float d = pe - te;
    float dist = sqrtf(d * d + 1e-6f);
    red[t] = dist * rw[r];
    __syncthreads();
    if (t == 0) {
        float tot = 0.0f;
        for (int i = 0; i < 384; ++i) tot += red[i];
        out[0] = tot / 384.0f;
    }
}

extern "C" void kernel_launch(void* const* d_in, const int* in_sizes, int n_in,
                              void* d_out, int out_size, void* d_ws, size_t ws_size,
                              hipStream_t stream) {
    const float* pred = (const float*)d_in[0];
    const float* tgt  = (const float*)d_in[1];
    const float* rw   = (const float*)d_in[2];

    char* ws = (char*)d_ws;
    float* acc    = (float*)ws;                     // 32*24 floats
    float* counts = acc + 32 * 24;                  // 24 floats
    unsigned char* mapT = (unsigned char*)(ws + 4096);      // 512*512 = 256 KB
    float2* buf   = (float2*)(ws + 4096 + 262144);  // 32*257*512 complex = 33.7 MB

    zero_kernel<<<4, 256, 0, stream>>>(acc, 32 * 24 + 24);
    map_kernel<<<1024, 256, 0, stream>>>(mapT, counts);
    rowfft_kernel<<<32 * 256, 256, 0, stream>>>(pred, tgt, buf);
    colfft_kernel<<<32 * 257, 256, 0, stream>>>(buf, mapT, acc);
    final_kernel<<<1, 384, 0, stream>>>(acc, counts, rw, (float*)d_out);
}